// Round 11
// baseline (131.796 us; speedup 1.0000x reference)
//
#include <hip/hip_runtime.h>

// Problem constants
#define B_  2
#define S_  1024
#define FIN 768
#define E_  768
#define H_  12
#define DH  64   // = FH = 64

typedef unsigned int uint;
typedef unsigned short ushort;
typedef __attribute__((ext_vector_type(8))) short short8;    // 8 bf16 (4 VGPRs)
typedef __attribute__((ext_vector_type(4))) float floatx4;   // MFMA acc

__device__ __forceinline__ ushort f2bf(float f) {   // RNE float->bf16 bits
    uint u = __float_as_uint(f);
    return (ushort)((u + 0x7fffu + ((u >> 16) & 1u)) >> 16);
}

__device__ __forceinline__ uint4 pack8(const ushort* p) {
    uint4 r;
    r.x = (uint)p[0] | ((uint)p[1] << 16);
    r.y = (uint)p[2] | ((uint)p[3] << 16);
    r.z = (uint)p[4] | ((uint)p[5] << 16);
    r.w = (uint)p[6] | ((uint)p[7] << 16);
    return r;
}

__device__ __forceinline__ void split8v(float4 a, float4 b, short8& hi, short8& lo) {
    float v[8] = {a.x, a.y, a.z, a.w, b.x, b.y, b.z, b.w};
    ushort h[8], l[8];
#pragma unroll
    for (int j = 0; j < 8; ++j) {
        h[j] = f2bf(v[j]);
        l[j] = f2bf(v[j] - __uint_as_float(((uint)h[j]) << 16));
    }
    uint4 H = pack8(h), L = pack8(l);
    hi = *(short8*)&H;
    lo = *(short8*)&L;
}

// ---------------------------------------------------------------------------
// helper: 64x64 matvec via MFMA with split-bf16 B planes in LDS (wave-private T)
// dual accumulator chains for ILP.
// ---------------------------------------------------------------------------
__device__ __forceinline__ void mfma_matvec(const float srcC[4][4], float* T,
                                            int lm, int lq,
                                            const ushort* WH, const ushort* WL,
                                            floatx4 out[4]) {
    __builtin_amdgcn_wave_barrier();
#pragma unroll
    for (int nt = 0; nt < 4; ++nt)
#pragma unroll
        for (int r = 0; r < 4; ++r)
            T[(lq * 4 + r) * 68 + nt * 16 + lm] = srcC[nt][r];
    __builtin_amdgcn_wave_barrier();
    float4 a00 = *(const float4*)&T[lm * 68 + lq * 8];
    float4 a01 = *(const float4*)&T[lm * 68 + lq * 8 + 4];
    float4 a10 = *(const float4*)&T[lm * 68 + 32 + lq * 8];
    float4 a11 = *(const float4*)&T[lm * 68 + 32 + lq * 8 + 4];
    __builtin_amdgcn_wave_barrier();
    short8 A0h, A0l, A1h, A1l;
    split8v(a00, a01, A0h, A0l);
    split8v(a10, a11, A1h, A1l);
#pragma unroll
    for (int nt = 0; nt < 4; ++nt) {
        const int row = (nt * 16 + lm) * 72;
        short8 b0h = *(const short8*)&WH[row + lq * 8];
        short8 b0l = *(const short8*)&WL[row + lq * 8];
        short8 b1h = *(const short8*)&WH[row + 32 + lq * 8];
        short8 b1l = *(const short8*)&WL[row + 32 + lq * 8];
        floatx4 acc0 = (floatx4)0.f, acc1 = (floatx4)0.f;
        acc0 = __builtin_amdgcn_mfma_f32_16x16x32_bf16(A0h, b0h, acc0, 0, 0, 0);
        acc0 = __builtin_amdgcn_mfma_f32_16x16x32_bf16(A0l, b0h, acc0, 0, 0, 0);
        acc0 = __builtin_amdgcn_mfma_f32_16x16x32_bf16(A0h, b0l, acc0, 0, 0, 0);
        acc1 = __builtin_amdgcn_mfma_f32_16x16x32_bf16(A1h, b1h, acc1, 0, 0, 0);
        acc1 = __builtin_amdgcn_mfma_f32_16x16x32_bf16(A1l, b1h, acc1, 0, 0, 0);
        acc1 = __builtin_amdgcn_mfma_f32_16x16x32_bf16(A1h, b1l, acc1, 0, 0, 0);
        out[nt] = acc0 + acc1;
    }
}

// ---------------------------------------------------------------------------
// K1 fused: embed + NNMF, fully self-contained (no k_conv). 384 blocks =
// (32 tok-grp of 64) x (12 heads). Embed stages with IN-LOOP fp32->split-bf16
// conversion inside the double-buffered pipeline (conversion hides under
// MFMA); W planes / r1inv are recomputed per block from nw during the phase-2
// LDS re-carve. Embed epilogue registers ARE nnmf's inpC.
// ---------------------------------------------------------------------------
__global__ __launch_bounds__(256) void k_embed_nnmf(const float* __restrict__ xs,
                                                    const float* __restrict__ ew,
                                                    const float* __restrict__ eb,
                                                    const float* __restrict__ nw,
                                                    float* __restrict__ hout,
                                                    float* __restrict__ hriout,
                                                    float* __restrict__ mp0) {
    __shared__ __align__(16) unsigned char smem[73728];
    ushort* const sm = (ushort*)smem;
    const int tid = threadIdx.x;
    const int bid = blockIdx.x;

    const int head = bid % 12;           // fastest -> consecutive blocks share x-tile
    const int tok0 = (bid / 12) * 64;

    const int wv = tid >> 6, lane = tid & 63;
    const int mbase = wv * 16;           // wave's 16-token rows
    const int lm = lane & 15, lq = lane >> 4;

    floatx4 accA[4], accB[4];
#pragma unroll
    for (int nt = 0; nt < 4; ++nt) { accA[nt] = (floatx4)0.f; accB[nt] = (floatx4)0.f; }

    // ---- embed phase (double-buffered LDS, in-loop conversion) ----
    // buffer layout: buf stride 18432 ushorts; planes AsH,AsL,BsH,BsL at +0,+4608,+9216,+13824
    const int srow = tid >> 2, skq = (tid & 3) * 16;
    const int off = srow * 72 + skq;
    const float* xrow = xs + (size_t)(tok0 + srow) * FIN + skq;
    const float* wrow = ew + (size_t)(head * 64 + srow) * FIN + skq;

    float4 qa[4], qb[4];
#pragma unroll
    for (int c = 0; c < 4; ++c) {
        qa[c] = *(const float4*)(xrow + c * 4);
        qb[c] = *(const float4*)(wrow + c * 4);
    }
    {   // convert + stage panel 0 -> buf 0
        ushort* b0 = sm;
        short8 h0, l0, h1, l1;
        split8v(qa[0], qa[1], h0, l0); split8v(qa[2], qa[3], h1, l1);
        *(short8*)&b0[off]            = h0;
        *(short8*)&b0[off + 8]        = h1;
        *(short8*)&b0[4608 + off]     = l0;
        *(short8*)&b0[4608 + off + 8] = l1;
        split8v(qb[0], qb[1], h0, l0); split8v(qb[2], qb[3], h1, l1);
        *(short8*)&b0[9216 + off]     = h0;
        *(short8*)&b0[9216 + off + 8] = h1;
        *(short8*)&b0[13824 + off]    = l0;
        *(short8*)&b0[13824 + off + 8]= l1;
    }
#pragma unroll
    for (int c = 0; c < 4; ++c) {   // load panel 1 (f32)
        qa[c] = *(const float4*)(xrow + 64 + c * 4);
        qb[c] = *(const float4*)(wrow + 64 + c * 4);
    }
    __syncthreads();

#pragma unroll 2
    for (int kb = 0; kb < 12; ++kb) {
        const int cur = kb & 1;
        const ushort* cb = sm + cur * 18432;
#pragma unroll
        for (int ch = 0; ch < 2; ++ch) {
            const int ko = ch * 32 + lq * 8;
            short8 ah = *(const short8*)&cb[(mbase + lm) * 72 + ko];
            short8 al = *(const short8*)&cb[4608 + (mbase + lm) * 72 + ko];
#pragma unroll
            for (int nt = 0; nt < 4; ++nt) {
                short8 bh = *(const short8*)&cb[9216 + (nt * 16 + lm) * 72 + ko];
                short8 bl = *(const short8*)&cb[13824 + (nt * 16 + lm) * 72 + ko];
                accA[nt] = __builtin_amdgcn_mfma_f32_16x16x32_bf16(ah, bh, accA[nt], 0, 0, 0);
                accB[nt] = __builtin_amdgcn_mfma_f32_16x16x32_bf16(al, bh, accB[nt], 0, 0, 0);
                accB[nt] = __builtin_amdgcn_mfma_f32_16x16x32_bf16(ah, bl, accB[nt], 0, 0, 0);
            }
        }
        if (kb + 1 < 12) {   // convert + stage panel kb+1 -> buf[cur^1]
            ushort* sb = sm + (cur ^ 1) * 18432;
            short8 h0, l0, h1, l1;
            split8v(qa[0], qa[1], h0, l0); split8v(qa[2], qa[3], h1, l1);
            *(short8*)&sb[off]            = h0;
            *(short8*)&sb[off + 8]        = h1;
            *(short8*)&sb[4608 + off]     = l0;
            *(short8*)&sb[4608 + off + 8] = l1;
            split8v(qb[0], qb[1], h0, l0); split8v(qb[2], qb[3], h1, l1);
            *(short8*)&sb[9216 + off]     = h0;
            *(short8*)&sb[9216 + off + 8] = h1;
            *(short8*)&sb[13824 + off]    = l0;
            *(short8*)&sb[13824 + off + 8]= l1;
        }
        if (kb + 2 < 12) {   // prefetch panel kb+2 (f32; lands during next panel)
            const int ko = (kb + 2) * 64;
#pragma unroll
            for (int c = 0; c < 4; ++c) {
                qa[c] = *(const float4*)(xrow + ko + c * 4);
                qb[c] = *(const float4*)(wrow + ko + c * 4);
            }
        }
        __syncthreads();
    }

    // embed epilogue: bias, clamp, per-token l1norm (wave-internal) -> inpC regs
    float inpC[4][4];
    {
        float bb[4];
#pragma unroll
        for (int nt = 0; nt < 4; ++nt) bb[nt] = eb[head * 64 + nt * 16 + lm];
#pragma unroll
        for (int r = 0; r < 4; ++r) {
            float e[4];
            float p = 0.f;
#pragma unroll
            for (int nt = 0; nt < 4; ++nt) {
                e[nt] = fmaxf((accA[nt][r] + accB[nt][r]) + bb[nt], 1e-6f);
                p += e[nt];
            }
            p += __shfl_xor(p, 1, 64);
            p += __shfl_xor(p, 2, 64);
            p += __shfl_xor(p, 4, 64);
            p += __shfl_xor(p, 8, 64);
            const float inv = 1.f / fmaxf(p, 1e-20f);
#pragma unroll
            for (int nt = 0; nt < 4; ++nt) inpC[nt][r] = e[nt] * inv;
        }
    }

    // ---- re-carve LDS; per-block W-prep from nw ----
    __syncthreads();   // embed buffers dead
    ushort* WtH = sm;                         // [64][72] each (stride-72 ushorts)
    ushort* WtL = sm + 4608;
    ushort* WwH = sm + 9216;
    ushort* WwL = sm + 13824;
    float*  Wl  = (float*)(smem + 36864);     // [64][65] fp32
    float*  Tb  = (float*)(smem + 53504);     // 4 waves x [16*68]
    float*  pbuf= (float*)(smem + 70912);     // [256]
    float*  T   = Tb + wv * (16 * 68);

    const int pf = tid >> 2, pq = tid & 3;
    {   // step A: normalize nw rows -> Wl + Ww planes (rows of Wn)
        float v[16];
        float s = 0.f;
#pragma unroll
        for (int i = 0; i < 16; ++i) { v[i] = nw[pf * 64 + pq * 16 + i]; s += v[i]; }
        s += __shfl_xor(s, 1, 64);
        s += __shfl_xor(s, 2, 64);
        const float inv = 1.f / fmaxf(s, 1e-20f);
        float w[16];
#pragma unroll
        for (int i = 0; i < 16; ++i) { w[i] = v[i] * inv; Wl[pf * 65 + pq * 16 + i] = w[i]; }
        short8 h0, l0, h1, l1;
        split8v(make_float4(w[0], w[1], w[2], w[3]),
                make_float4(w[4], w[5], w[6], w[7]), h0, l0);
        split8v(make_float4(w[8], w[9], w[10], w[11]),
                make_float4(w[12], w[13], w[14], w[15]), h1, l1);
        const int l = pf * 72 + pq * 16;
        *(short8*)&WwH[l]     = h0;
        *(short8*)&WwH[l + 8] = h1;
        *(short8*)&WwL[l]     = l0;
        *(short8*)&WwL[l + 8] = l1;
    }
    __syncthreads();   // Wl ready
    {   // step B: Wt planes (rows of WnT) from Wl
        float t[16];
#pragma unroll
        for (int i = 0; i < 16; ++i) t[i] = Wl[(pq * 16 + i) * 65 + pf];
        short8 h0, l0, h1, l1;
        split8v(make_float4(t[0], t[1], t[2], t[3]),
                make_float4(t[4], t[5], t[6], t[7]), h0, l0);
        split8v(make_float4(t[8], t[9], t[10], t[11]),
                make_float4(t[12], t[13], t[14], t[15]), h1, l1);
        const int l = pf * 72 + pq * 16;
        *(short8*)&WtH[l]     = h0;
        *(short8*)&WtH[l + 8] = h1;
        *(short8*)&WtL[l]     = l0;
        *(short8*)&WtL[l + 8] = l1;
    }
    if (tid < 64) {   // r1inv into pbuf[0..63]
        float cs = 0.f;
        for (int ff = 0; ff < 64; ++ff) cs += Wl[ff * 65 + tid];
        float t = fmaxf(cs * (1.f / 64.f), 1e-6f);
        float S = t;
#pragma unroll
        for (int m = 1; m < 64; m <<= 1) S += __shfl_xor(S, m, 64);
        S = fmaxf(S, 1e-20f);
        pbuf[tid] = S / t;
    }
    __syncthreads();   // planes + r1 ready
    float r1c[4];
#pragma unroll
    for (int nt = 0; nt < 4; ++nt) r1c[nt] = pbuf[nt * 16 + lm];

    const size_t obase = ((size_t)((tok0 >> 10) * 12 + head) * 1024 + (tok0 & 1023));
    const size_t rowbase = obase + wv * 16;

    float hC[4][4], recC[4][4];
    {   // ---- iteration 1 (rec1 token-independent) ----
        float qC[4][4];
#pragma unroll
        for (int nt = 0; nt < 4; ++nt)
#pragma unroll
            for (int r = 0; r < 4; ++r) qC[nt][r] = inpC[nt][r] * r1c[nt];
        floatx4 u[4];
        mfma_matvec(qC, T, lm, lq, WwH, WwL, u);
#pragma unroll
        for (int nt = 0; nt < 4; ++nt)
#pragma unroll
            for (int r = 0; r < 4; ++r)
                hC[nt][r] = fmaxf(u[nt][r] * (1.f / 64.f), 1e-6f);
#pragma unroll
        for (int r = 0; r < 4; ++r) {
            float s = (hC[0][r] + hC[1][r]) + (hC[2][r] + hC[3][r]);
            s += __shfl_xor(s, 1, 64); s += __shfl_xor(s, 2, 64);
            s += __shfl_xor(s, 4, 64); s += __shfl_xor(s, 8, 64);
            const float inv = __builtin_amdgcn_rcpf(fmaxf(s, 1e-20f));
#pragma unroll
            for (int nt = 0; nt < 4; ++nt) hC[nt][r] *= inv;
        }
    }
#pragma unroll 1
    for (int it = 0; it < 2; ++it) {   // ---- iterations 2,3 (full) ----
        floatx4 t[4];
        mfma_matvec(hC, T, lm, lq, WtH, WtL, t);
        float tC[4][4], qC[4][4];
#pragma unroll
        for (int nt = 0; nt < 4; ++nt)
#pragma unroll
            for (int r = 0; r < 4; ++r) tC[nt][r] = fmaxf(t[nt][r], 1e-6f);
#pragma unroll
        for (int r = 0; r < 4; ++r) {
            float s = (tC[0][r] + tC[1][r]) + (tC[2][r] + tC[3][r]);
            s += __shfl_xor(s, 1, 64); s += __shfl_xor(s, 2, 64);
            s += __shfl_xor(s, 4, 64); s += __shfl_xor(s, 8, 64);
            s = fmaxf(s, 1e-20f);
            const float invS = __builtin_amdgcn_rcpf(s);
#pragma unroll
            for (int nt = 0; nt < 4; ++nt) {
                recC[nt][r] = tC[nt][r] * invS;
                qC[nt][r] = inpC[nt][r] * s * __builtin_amdgcn_rcpf(tC[nt][r]);
            }
        }
        floatx4 u[4];
        mfma_matvec(qC, T, lm, lq, WwH, WwL, u);
#pragma unroll
        for (int nt = 0; nt < 4; ++nt)
#pragma unroll
            for (int r = 0; r < 4; ++r)
                hC[nt][r] = fmaxf(hC[nt][r] * u[nt][r], 1e-6f);
#pragma unroll
        for (int r = 0; r < 4; ++r) {
            float s = (hC[0][r] + hC[1][r]) + (hC[2][r] + hC[3][r]);
            s += __shfl_xor(s, 1, 64); s += __shfl_xor(s, 2, 64);
            s += __shfl_xor(s, 4, 64); s += __shfl_xor(s, 8, 64);
            const float inv = __builtin_amdgcn_rcpf(fmaxf(s, 1e-20f));
#pragma unroll
            for (int nt = 0; nt < 4; ++nt) hC[nt][r] *= inv;
        }
    }
#pragma unroll
    for (int r = 0; r < 4; ++r) {   // normalize_h
        float s = (hC[0][r] + hC[1][r]) + (hC[2][r] + hC[3][r]);
        s += __shfl_xor(s, 1, 64); s += __shfl_xor(s, 2, 64);
        s += __shfl_xor(s, 4, 64); s += __shfl_xor(s, 8, 64);
        const float inv = __builtin_amdgcn_rcpf(fmaxf(s, 1e-20f));
#pragma unroll
        for (int nt = 0; nt < 4; ++nt) hC[nt][r] *= inv;
    }

    // stores: h, rec*inp row-major [o][f]
#pragma unroll
    for (int nt = 0; nt < 4; ++nt)
#pragma unroll
        for (int r = 0; r < 4; ++r) {
            const size_t o = (rowbase + lq * 4 + r) * 64 + nt * 16 + lm;
            hout[o] = hC[nt][r];
            hriout[o] = recC[nt][r] * inpC[nt][r];
        }

    // per-block partial of sum_o h[o,f]: wave-reduce + LDS combine + plain store
    float hs[4];
#pragma unroll
    for (int nt = 0; nt < 4; ++nt) {
        float s = (hC[nt][0] + hC[nt][1]) + (hC[nt][2] + hC[nt][3]);
        s += __shfl_xor(s, 16, 64);
        s += __shfl_xor(s, 32, 64);
        hs[nt] = s;
    }
    __syncthreads();   // r1 reads long done; pbuf reused for partials
    pbuf[wv * 64 + lq * 16 + lm] = hs[lq];
    __syncthreads();
    if (tid < 64) {
        float tot = (pbuf[tid] + pbuf[64 + tid]) + (pbuf[128 + tid] + pbuf[192 + tid]);
        mp0[(obase >> 6) * 64 + tid] = tot;
    }
}

// ---------------------------------------------------------------------------
// K4: one alpha iteration per launch, 384 blocks = (bh) x (64-o chunk).
// Wn recomputed per block from nw (no global Wn). Exclusive plain stores.
// ---------------------------------------------------------------------------
__global__ __launch_bounds__(256) void k_alpha_step(const float* __restrict__ hin,
                                                    const float* __restrict__ hri,
                                                    const float* __restrict__ nw,
                                                    const float* __restrict__ mp_in,
                                                    float* __restrict__ mp_out,
                                                    float* __restrict__ c,
                                                    int it) {
    __shared__ float Wnl[64 * 65];
    __shared__ float mred[4][64];
    __shared__ float mv[64];
    __shared__ float vv[64];
    __shared__ float cl[64];
    const int tid = threadIdx.x;
    const int bh = blockIdx.x >> 4;
    const int chunk = blockIdx.x & 15;
    const size_t rowbase = (size_t)bh * 1024 + chunk * 64;

    {   // per-block W normalize: row pf, quarter pq
        const int pf = tid >> 2, pq = tid & 3;
        float v[16];
        float s = 0.f;
#pragma unroll
        for (int i = 0; i < 16; ++i) { v[i] = nw[pf * 64 + pq * 16 + i]; s += v[i]; }
        s += __shfl_xor(s, 1, 64);
        s += __shfl_xor(s, 2, 64);
        const float inv = 1.f / fmaxf(s, 1e-20f);
#pragma unroll
        for (int i = 0; i < 16; ++i) Wnl[pf * 65 + pq * 16 + i] = v[i] * inv;
    }
    {
        int f = tid & 63, p = tid >> 6;
        float s = 0.f;
#pragma unroll
        for (int pp = 0; pp < 4; ++pp)
            s += mp_in[((size_t)bh * 16 + p * 4 + pp) * 64 + f];
        mred[p][f] = s;
    }
    __syncthreads();
    if (tid < 64)
        mv[tid] = (mred[0][tid] + mred[1][tid]) + (mred[2][tid] + mred[3][tid]);
    __syncthreads();
    {
        int d = tid & 63, qq = tid >> 6;
        float r = 0.f;
#pragma unroll
        for (int ff = 0; ff < 16; ++ff)
            r = fmaf(mv[qq * 16 + ff], Wnl[(qq * 16 + ff) * 65 + d], r);
        mred[qq][d] = r;
    }
    __syncthreads();
    if (tid < 64)
        vv[tid] = 1.f / (((mred[0][tid] + mred[1][tid]) + (mred[2][tid] + mred[3][tid])) + 1e-20f);
    __syncthreads();
    {
        int o = tid >> 2, dq = tid & 3;
        const float* rp = hri + (rowbase + o) * 64 + dq * 16;
        float dot = 0.f;
#pragma unroll
        for (int t4 = 0; t4 < 16; t4 += 4) {
            float4 r4 = *(const float4*)(rp + t4);
            dot = fmaf(r4.x, vv[dq * 16 + t4 + 0], dot);
            dot = fmaf(r4.y, vv[dq * 16 + t4 + 1], dot);
            dot = fmaf(r4.z, vv[dq * 16 + t4 + 2], dot);
            dot = fmaf(r4.w, vv[dq * 16 + t4 + 3], dot);
        }
        dot += __shfl_xor(dot, 1, 64);
        dot += __shfl_xor(dot, 2, 64);
        float cn = dot;
        if (it >= 2) cn *= c[rowbase + o];
        if (dq == 0) { c[rowbase + o] = cn; cl[o] = cn; }
    }
    __syncthreads();
    {
        const int f4 = (tid & 15) * 4, ogr = tid >> 4;
        float4 a = make_float4(0.f, 0.f, 0.f, 0.f);
#pragma unroll
        for (int oi = 0; oi < 4; ++oi) {
            int o = ogr * 4 + oi;
            float4 h4 = *(const float4*)(hin + (rowbase + o) * 64 + f4);
            float cv = cl[o];
            a.x = fmaf(h4.x, cv, a.x); a.y = fmaf(h4.y, cv, a.y);
            a.z = fmaf(h4.z, cv, a.z); a.w = fmaf(h4.w, cv, a.w);
        }
        a.x += __shfl_xor(a.x, 16, 64); a.y += __shfl_xor(a.y, 16, 64);
        a.z += __shfl_xor(a.z, 16, 64); a.w += __shfl_xor(a.w, 16, 64);
        a.x += __shfl_xor(a.x, 32, 64); a.y += __shfl_xor(a.y, 32, 64);
        a.z += __shfl_xor(a.z, 32, 64); a.w += __shfl_xor(a.w, 32, 64);
        const int w = tid >> 6;
        if ((tid & 63) < 16) *(float4*)&mred[w][(tid & 15) * 4] = a;
    }
    __syncthreads();
    if (tid < 64) {
        float s = (mred[0][tid] + mred[1][tid]) + (mred[2][tid] + mred[3][tid]);
        mp_out[((size_t)bh * 16 + chunk) * 64 + tid] = s;
    }
}

// ---------------------------------------------------------------------------
// K5: out-projection + broadcast, 384 blocks = (b) x (12 out-seg) x (16 rowgrp).
// Folds the final 16-chunk M reduction into the Ml load.
// ---------------------------------------------------------------------------
__global__ __launch_bounds__(256) void k_projbcast(const float* __restrict__ mp3,
                                                   const float* __restrict__ ow,
                                                   const float* __restrict__ ob,
                                                   float* __restrict__ out) {
    __shared__ float Ml[768];
    __shared__ float ps[4][64];
    __shared__ float yseg[64];
    const int tid = threadIdx.x;
    const int b = blockIdx.x / 192;
    const int rem = blockIdx.x - b * 192;
    const int jt = rem >> 4, rg = rem & 15;
    for (int i = tid; i < 768; i += 256) {
        const int hh = i >> 6, f = i & 63;
        const float* src = mp3 + ((size_t)(b * 12 + hh) * 16) * 64 + f;
        float s = 0.f;
#pragma unroll
        for (int cc = 0; cc < 16; ++cc) s += src[cc * 64];
        Ml[i] = s;
    }
    __syncthreads();
    const int jj = tid & 63, part = tid >> 6;
    const int j = jt * 64 + jj;
    const float* row = ow + (size_t)j * 768 + part * 192;
    float acc = 0.f;
    for (int t = 0; t < 192; t += 4) {
        float4 w4 = *(const float4*)(row + t);
        acc = fmaf(w4.x, Ml[part * 192 + t + 0], acc);
        acc = fmaf(w4.y, Ml[part * 192 + t + 1], acc);
        acc = fmaf(w4.z, Ml[part * 192 + t + 2], acc);
        acc = fmaf(w4.w, Ml[part * 192 + t + 3], acc);
    }
    ps[part][jj] = acc;
    __syncthreads();
    if (tid < 64)
        yseg[tid] = ps[0][tid] + ps[1][tid] + ps[2][tid] + ps[3][tid] + ob[jt * 64 + tid];
    __syncthreads();
    const int r0 = tid >> 2, c4 = (tid & 3) * 16;
    float4 v4[4];
#pragma unroll
    for (int q = 0; q < 4; ++q) v4[q] = *(const float4*)&yseg[c4 + q * 4];
    float* dst = out + ((size_t)(b * 1024 + rg * 64 + r0)) * 768 + jt * 64 + c4;
#pragma unroll
    for (int q = 0; q < 4; ++q) *(float4*)(dst + q * 4) = v4[q];
}

extern "C" void kernel_launch(void* const* d_in, const int* in_sizes, int n_in,
                              void* d_out, int out_size, void* d_ws, size_t ws_size,
                              hipStream_t stream) {
    const float* xs = (const float*)d_in[0];  // [2,1024,768]
    const float* ew = (const float*)d_in[1];  // [768,768]
    const float* eb = (const float*)d_in[2];  // [768]
    const float* nw = (const float*)d_in[3];  // [64,64]
    const float* ow = (const float*)d_in[4];  // [768,768]
    const float* ob = (const float*)d_in[5];  // [768]
    float* out = (float*)d_out;               // [2,1024,768]

    float* ws  = (float*)d_ws;
    float* h   = ws;                   // 1572864 f
    float* hri = ws + 1572864;         // 1572864 f
    float* mp0 = ws + 3145728;         // 24576 f
    float* mp1 = ws + 3170304;         // 24576 f
    float* mp2 = ws + 3194880;         // 24576 f
    float* c   = ws + 3219456;         // 24576 f

    k_embed_nnmf<<<384, 256, 0, stream>>>(xs, ew, eb, nw, h, hri, mp0);
    k_alpha_step<<<384, 256, 0, stream>>>(h, hri, nw, mp0, mp1, c, 1);
    k_alpha_step<<<384, 256, 0, stream>>>(h, hri, nw, mp1, mp2, c, 2);
    k_alpha_step<<<384, 256, 0, stream>>>(h, hri, nw, mp2, mp1, c, 3);
    k_projbcast<<<384, 256, 0, stream>>>(mp1, ow, ob, out);
}

// Round 12
// 128.720 us; speedup vs baseline: 1.0239x; 1.0239x over previous
//
#include <hip/hip_runtime.h>

// Problem constants
#define B_  2
#define S_  1024
#define FIN 768
#define E_  768
#define H_  12
#define DH  64   // = FH = 64

typedef unsigned int uint;
typedef unsigned short ushort;
typedef __attribute__((ext_vector_type(8))) short short8;    // 8 bf16 (4 VGPRs)
typedef __attribute__((ext_vector_type(4))) float floatx4;   // MFMA acc

__device__ __forceinline__ ushort f2bf(float f) {   // RNE float->bf16 bits
    uint u = __float_as_uint(f);
    return (ushort)((u + 0x7fffu + ((u >> 16) & 1u)) >> 16);
}

__device__ __forceinline__ uint4 pack8(const ushort* p) {
    uint4 r;
    r.x = (uint)p[0] | ((uint)p[1] << 16);
    r.y = (uint)p[2] | ((uint)p[3] << 16);
    r.z = (uint)p[4] | ((uint)p[5] << 16);
    r.w = (uint)p[6] | ((uint)p[7] << 16);
    return r;
}

__device__ __forceinline__ void split8v(float4 a, float4 b, short8& hi, short8& lo) {
    float v[8] = {a.x, a.y, a.z, a.w, b.x, b.y, b.z, b.w};
    ushort h[8], l[8];
#pragma unroll
    for (int j = 0; j < 8; ++j) {
        h[j] = f2bf(v[j]);
        l[j] = f2bf(v[j] - __uint_as_float(((uint)h[j]) << 16));
    }
    uint4 H = pack8(h), L = pack8(l);
    hi = *(short8*)&H;
    lo = *(short8*)&L;
}

// ---------------------------------------------------------------------------
// K0: conversion + prep pass. blocks 0..767: xs -> xsH/xsL bf16 split planes.
// blocks 768..1055: ew -> ewH/ewL. block 1056: W-prep (Wn, r1inv, Wfrag).
// Pre-conversion is load-bearing: operands are reused (12 blocks per x-tile,
// 32 per ew-row), so converting once here beats in-kernel conversion (R11).
// ---------------------------------------------------------------------------
__global__ __launch_bounds__(256) void k_conv(const float* __restrict__ xs,
                                              const float* __restrict__ ew,
                                              const float* __restrict__ nw,
                                              ushort* __restrict__ xsH,
                                              ushort* __restrict__ xsL,
                                              ushort* __restrict__ ewH,
                                              ushort* __restrict__ ewL,
                                              float* __restrict__ Wn,
                                              float* __restrict__ r1inv,
                                              ushort* __restrict__ Wfrag) {
    __shared__ float Wl[64 * 65];
    const int tid = threadIdx.x, bid = blockIdx.x;

    if (bid < 768) {          // xs conversion: 2048x768 / 8 per thread
        const size_t i = ((size_t)bid * 256 + tid) * 8;
        short8 hi, lo;
        split8v(*(const float4*)(xs + i), *(const float4*)(xs + i + 4), hi, lo);
        *(short8*)(xsH + i) = hi;
        *(short8*)(xsL + i) = lo;
        return;
    }
    if (bid < 1056) {         // ew conversion: 768x768 / 8 per thread
        const size_t i = ((size_t)(bid - 768) * 256 + tid) * 8;
        short8 hi, lo;
        split8v(*(const float4*)(ew + i), *(const float4*)(ew + i + 4), hi, lo);
        *(short8*)(ewH + i) = hi;
        *(short8*)(ewL + i) = lo;
        return;
    }

    // ---- prep block (bid == 1056) ----
    const int f = tid >> 2, q = tid & 3;
    float v[16];
    float s = 0.f;
#pragma unroll
    for (int i = 0; i < 16; ++i) { v[i] = nw[f * 64 + q * 16 + i]; s += v[i]; }
    s += __shfl_xor(s, 1, 64);
    s += __shfl_xor(s, 2, 64);
    const float inv = 1.f / fmaxf(s, 1e-20f);
    float w[16];
#pragma unroll
    for (int i = 0; i < 16; ++i) {
        w[i] = v[i] * inv;
        Wn[f * 64 + q * 16 + i] = w[i];
        Wl[f * 65 + q * 16 + i] = w[i];
    }
    __syncthreads();
    if (tid < 64) {
        float cs = 0.f;
        for (int ff = 0; ff < 64; ++ff) cs += Wl[ff * 65 + tid];
        float t = fmaxf(cs * (1.f / 64.f), 1e-6f);
        float S = t;
#pragma unroll
        for (int m = 1; m < 64; m <<= 1) S += __shfl_xor(S, m, 64);
        S = fmaxf(S, 1e-20f);
        r1inv[tid] = S / t;   // 1/rec1
    }
    // Ww planes (rows of Wn) from registers: row f, quarter q
    {
        short8 h0, l0, h1, l1;
        split8v(make_float4(w[0], w[1], w[2], w[3]),
                make_float4(w[4], w[5], w[6], w[7]), h0, l0);
        split8v(make_float4(w[8], w[9], w[10], w[11]),
                make_float4(w[12], w[13], w[14], w[15]), h1, l1);
        ushort* WwH = Wfrag + 2 * 4096;
        ushort* WwL = Wfrag + 3 * 4096;
        *(short8*)(WwH + f * 64 + q * 16) = h0;
        *(short8*)(WwH + f * 64 + q * 16 + 8) = h1;
        *(short8*)(WwL + f * 64 + q * 16) = l0;
        *(short8*)(WwL + f * 64 + q * 16 + 8) = l1;
    }
    // Wt planes (rows of WnT) from LDS: WnT[f][q*16+i] = Wn[q*16+i][f]
    {
        float t[16];
#pragma unroll
        for (int i = 0; i < 16; ++i) t[i] = Wl[(q * 16 + i) * 65 + f];
        short8 h0, l0, h1, l1;
        split8v(make_float4(t[0], t[1], t[2], t[3]),
                make_float4(t[4], t[5], t[6], t[7]), h0, l0);
        split8v(make_float4(t[8], t[9], t[10], t[11]),
                make_float4(t[12], t[13], t[14], t[15]), h1, l1);
        ushort* WtH = Wfrag;
        ushort* WtL = Wfrag + 4096;
        *(short8*)(WtH + f * 64 + q * 16) = h0;
        *(short8*)(WtH + f * 64 + q * 16 + 8) = h1;
        *(short8*)(WtL + f * 64 + q * 16) = l0;
        *(short8*)(WtL + f * 64 + q * 16 + 8) = l1;
    }
}

// ---------------------------------------------------------------------------
// helper: 64x64 matvec via MFMA with split-bf16 B planes in LDS (wave-private T)
// dual accumulator chains for ILP.
// ---------------------------------------------------------------------------
__device__ __forceinline__ void mfma_matvec(const float srcC[4][4], float* T,
                                            int lm, int lq,
                                            const ushort* WH, const ushort* WL,
                                            floatx4 out[4]) {
    __builtin_amdgcn_wave_barrier();
#pragma unroll
    for (int nt = 0; nt < 4; ++nt)
#pragma unroll
        for (int r = 0; r < 4; ++r)
            T[(lq * 4 + r) * 68 + nt * 16 + lm] = srcC[nt][r];
    __builtin_amdgcn_wave_barrier();
    float4 a00 = *(const float4*)&T[lm * 68 + lq * 8];
    float4 a01 = *(const float4*)&T[lm * 68 + lq * 8 + 4];
    float4 a10 = *(const float4*)&T[lm * 68 + 32 + lq * 8];
    float4 a11 = *(const float4*)&T[lm * 68 + 32 + lq * 8 + 4];
    __builtin_amdgcn_wave_barrier();
    short8 A0h, A0l, A1h, A1l;
    split8v(a00, a01, A0h, A0l);
    split8v(a10, a11, A1h, A1l);
#pragma unroll
    for (int nt = 0; nt < 4; ++nt) {
        const int row = (nt * 16 + lm) * 72;
        short8 b0h = *(const short8*)&WH[row + lq * 8];
        short8 b0l = *(const short8*)&WL[row + lq * 8];
        short8 b1h = *(const short8*)&WH[row + 32 + lq * 8];
        short8 b1l = *(const short8*)&WL[row + 32 + lq * 8];
        floatx4 acc0 = (floatx4)0.f, acc1 = (floatx4)0.f;
        acc0 = __builtin_amdgcn_mfma_f32_16x16x32_bf16(A0h, b0h, acc0, 0, 0, 0);
        acc0 = __builtin_amdgcn_mfma_f32_16x16x32_bf16(A0l, b0h, acc0, 0, 0, 0);
        acc0 = __builtin_amdgcn_mfma_f32_16x16x32_bf16(A0h, b0l, acc0, 0, 0, 0);
        acc1 = __builtin_amdgcn_mfma_f32_16x16x32_bf16(A1h, b1h, acc1, 0, 0, 0);
        acc1 = __builtin_amdgcn_mfma_f32_16x16x32_bf16(A1l, b1h, acc1, 0, 0, 0);
        acc1 = __builtin_amdgcn_mfma_f32_16x16x32_bf16(A1h, b1l, acc1, 0, 0, 0);
        out[nt] = acc0 + acc1;
    }
}

// ---------------------------------------------------------------------------
// K1 fused: embed + NNMF in one kernel. 384 blocks = (32 tok-grp of 64) x
// (12 heads), identical decomposition for both phases — embed's epilogue
// registers ARE nnmf's inpC (no inp global round-trip, one fewer launch).
// LDS time-sliced: embed dbuf (73.7 KB) -> nnmf W-planes + T (55.3 KB).
// ---------------------------------------------------------------------------
__global__ __launch_bounds__(256) void k_embed_nnmf(const ushort* __restrict__ xsH,
                                                    const ushort* __restrict__ xsL,
                                                    const ushort* __restrict__ ewH,
                                                    const ushort* __restrict__ ewL,
                                                    const float* __restrict__ eb,
                                                    const ushort* __restrict__ Wfrag,
                                                    const float* __restrict__ r1inv,
                                                    float* __restrict__ hout,
                                                    float* __restrict__ hriout,
                                                    float* __restrict__ mp0) {
    __shared__ __align__(16) unsigned char smem[73728];
    ushort* const sm = (ushort*)smem;
    const int tid = threadIdx.x;
    const int bid = blockIdx.x;

    const int head = bid % 12;           // fastest -> consecutive blocks share x-tile
    const int tok0 = (bid / 12) * 64;

    const int wv = tid >> 6, lane = tid & 63;
    const int mbase = wv * 16;           // wave's 16-token rows
    const int lm = lane & 15, lq = lane >> 4;

    floatx4 accA[4], accB[4];
#pragma unroll
    for (int nt = 0; nt < 4; ++nt) { accA[nt] = (floatx4)0.f; accB[nt] = (floatx4)0.f; }

    // ---- embed phase (double-buffered LDS, 1 barrier/panel) ----
    // buffer layout: buf stride 18432 ushorts; planes AsH,AsL,BsH,BsL at +0,+4608,+9216,+13824
    const int srow = tid >> 2, skq = (tid & 3) * 16;
    const int off = srow * 72 + skq;
    const ushort* xh = xsH + (size_t)(tok0 + srow) * FIN + skq;
    const ushort* xl = xsL + (size_t)(tok0 + srow) * FIN + skq;
    const ushort* wh = ewH + (size_t)(head * 64 + srow) * FIN + skq;
    const ushort* wl = ewL + (size_t)(head * 64 + srow) * FIN + skq;

    short8 pa[4], pb[4];
    pa[0] = *(const short8*)(xh);  pa[1] = *(const short8*)(xh + 8);
    pa[2] = *(const short8*)(xl);  pa[3] = *(const short8*)(xl + 8);
    pb[0] = *(const short8*)(wh);  pb[1] = *(const short8*)(wh + 8);
    pb[2] = *(const short8*)(wl);  pb[3] = *(const short8*)(wl + 8);
    {
        ushort* b0 = sm;
        *(short8*)&b0[off]            = pa[0];
        *(short8*)&b0[off + 8]        = pa[1];
        *(short8*)&b0[4608 + off]     = pa[2];
        *(short8*)&b0[4608 + off + 8] = pa[3];
        *(short8*)&b0[9216 + off]     = pb[0];
        *(short8*)&b0[9216 + off + 8] = pb[1];
        *(short8*)&b0[13824 + off]    = pb[2];
        *(short8*)&b0[13824 + off + 8]= pb[3];
    }
    pa[0] = *(const short8*)(xh + 64);  pa[1] = *(const short8*)(xh + 72);
    pa[2] = *(const short8*)(xl + 64);  pa[3] = *(const short8*)(xl + 72);
    pb[0] = *(const short8*)(wh + 64);  pb[1] = *(const short8*)(wh + 72);
    pb[2] = *(const short8*)(wl + 64);  pb[3] = *(const short8*)(wl + 72);
    __syncthreads();

#pragma unroll 2
    for (int kb = 0; kb < 12; ++kb) {
        const int cur = kb & 1;
        const ushort* cb = sm + cur * 18432;
#pragma unroll
        for (int ch = 0; ch < 2; ++ch) {
            const int ko = ch * 32 + lq * 8;
            short8 ah = *(const short8*)&cb[(mbase + lm) * 72 + ko];
            short8 al = *(const short8*)&cb[4608 + (mbase + lm) * 72 + ko];
#pragma unroll
            for (int nt = 0; nt < 4; ++nt) {
                short8 bh = *(const short8*)&cb[9216 + (nt * 16 + lm) * 72 + ko];
                short8 bl = *(const short8*)&cb[13824 + (nt * 16 + lm) * 72 + ko];
                accA[nt] = __builtin_amdgcn_mfma_f32_16x16x32_bf16(ah, bh, accA[nt], 0, 0, 0);
                accB[nt] = __builtin_amdgcn_mfma_f32_16x16x32_bf16(al, bh, accB[nt], 0, 0, 0);
                accB[nt] = __builtin_amdgcn_mfma_f32_16x16x32_bf16(ah, bl, accB[nt], 0, 0, 0);
            }
        }
        if (kb + 1 < 12) {
            ushort* sb = sm + (cur ^ 1) * 18432;
            *(short8*)&sb[off]            = pa[0];
            *(short8*)&sb[off + 8]        = pa[1];
            *(short8*)&sb[4608 + off]     = pa[2];
            *(short8*)&sb[4608 + off + 8] = pa[3];
            *(short8*)&sb[9216 + off]     = pb[0];
            *(short8*)&sb[9216 + off + 8] = pb[1];
            *(short8*)&sb[13824 + off]    = pb[2];
            *(short8*)&sb[13824 + off + 8]= pb[3];
        }
        if (kb + 2 < 12) {
            const int ko = (kb + 2) * 64;
            pa[0] = *(const short8*)(xh + ko);  pa[1] = *(const short8*)(xh + ko + 8);
            pa[2] = *(const short8*)(xl + ko);  pa[3] = *(const short8*)(xl + ko + 8);
            pb[0] = *(const short8*)(wh + ko);  pb[1] = *(const short8*)(wh + ko + 8);
            pb[2] = *(const short8*)(wl + ko);  pb[3] = *(const short8*)(wl + ko + 8);
        }
        __syncthreads();
    }

    // prefetch W fragment planes + r1inv during the epilogue (LDS still busy)
    const int wrow = tid >> 2, wkq = (tid & 3) * 16;
    const int wg = wrow * 64 + wkq;
    short8 wt0 = *(const short8*)(Wfrag + wg);
    short8 wt1 = *(const short8*)(Wfrag + wg + 8);
    short8 wt2 = *(const short8*)(Wfrag + 4096 + wg);
    short8 wt3 = *(const short8*)(Wfrag + 4096 + wg + 8);
    short8 ww0 = *(const short8*)(Wfrag + 8192 + wg);
    short8 ww1 = *(const short8*)(Wfrag + 8192 + wg + 8);
    short8 ww2 = *(const short8*)(Wfrag + 12288 + wg);
    short8 ww3 = *(const short8*)(Wfrag + 12288 + wg + 8);
    float r1c[4];
#pragma unroll
    for (int nt = 0; nt < 4; ++nt) r1c[nt] = r1inv[nt * 16 + lm];

    // embed epilogue: bias, clamp, per-token l1norm (wave-internal) -> inpC regs
    float inpC[4][4];
    {
        float bb[4];
#pragma unroll
        for (int nt = 0; nt < 4; ++nt) bb[nt] = eb[head * 64 + nt * 16 + lm];
#pragma unroll
        for (int r = 0; r < 4; ++r) {
            float e[4];
            float p = 0.f;
#pragma unroll
            for (int nt = 0; nt < 4; ++nt) {
                e[nt] = fmaxf((accA[nt][r] + accB[nt][r]) + bb[nt], 1e-6f);
                p += e[nt];
            }
            p += __shfl_xor(p, 1, 64);
            p += __shfl_xor(p, 2, 64);
            p += __shfl_xor(p, 4, 64);
            p += __shfl_xor(p, 8, 64);
            const float inv = 1.f / fmaxf(p, 1e-20f);
#pragma unroll
            for (int nt = 0; nt < 4; ++nt) inpC[nt][r] = e[nt] * inv;
        }
    }

    // ---- re-carve LDS for nnmf phase ----
    __syncthreads();   // embed buffers dead
    ushort* WtH = sm;                         // [64][72] each
    ushort* WtL = sm + 4608;
    ushort* WwH = sm + 9216;
    ushort* WwL = sm + 13824;
    float*  Tb  = (float*)(smem + 36864);     // 4 waves x [16*68]
    float*  pbuf= (float*)(smem + 54272);     // [256]
    float*  T   = Tb + wv * (16 * 68);
    {
        const int l = wrow * 72 + wkq;
        *(short8*)&WtH[l]     = wt0;
        *(short8*)&WtH[l + 8] = wt1;
        *(short8*)&WtL[l]     = wt2;
        *(short8*)&WtL[l + 8] = wt3;
        *(short8*)&WwH[l]     = ww0;
        *(short8*)&WwH[l + 8] = ww1;
        *(short8*)&WwL[l]     = ww2;
        *(short8*)&WwL[l + 8] = ww3;
    }
    __syncthreads();   // W planes ready

    const size_t obase = ((size_t)((tok0 >> 10) * 12 + head) * 1024 + (tok0 & 1023));
    const size_t rowbase = obase + wv * 16;

    float hC[4][4], recC[4][4];
    {   // ---- iteration 1 (rec1 token-independent) ----
        float qC[4][4];
#pragma unroll
        for (int nt = 0; nt < 4; ++nt)
#pragma unroll
            for (int r = 0; r < 4; ++r) qC[nt][r] = inpC[nt][r] * r1c[nt];
        floatx4 u[4];
        mfma_matvec(qC, T, lm, lq, WwH, WwL, u);
#pragma unroll
        for (int nt = 0; nt < 4; ++nt)
#pragma unroll
            for (int r = 0; r < 4; ++r)
                hC[nt][r] = fmaxf(u[nt][r] * (1.f / 64.f), 1e-6f);
#pragma unroll
        for (int r = 0; r < 4; ++r) {
            float s = (hC[0][r] + hC[1][r]) + (hC[2][r] + hC[3][r]);
            s += __shfl_xor(s, 1, 64); s += __shfl_xor(s, 2, 64);
            s += __shfl_xor(s, 4, 64); s += __shfl_xor(s, 8, 64);
            const float inv = __builtin_amdgcn_rcpf(fmaxf(s, 1e-20f));
#pragma unroll
            for (int nt = 0; nt < 4; ++nt) hC[nt][r] *= inv;
        }
    }
#pragma unroll 1
    for (int it = 0; it < 2; ++it) {   // ---- iterations 2,3 (full) ----
        floatx4 t[4];
        mfma_matvec(hC, T, lm, lq, WtH, WtL, t);
        float tC[4][4], qC[4][4];
#pragma unroll
        for (int nt = 0; nt < 4; ++nt)
#pragma unroll
            for (int r = 0; r < 4; ++r) tC[nt][r] = fmaxf(t[nt][r], 1e-6f);
#pragma unroll
        for (int r = 0; r < 4; ++r) {
            float s = (tC[0][r] + tC[1][r]) + (tC[2][r] + tC[3][r]);
            s += __shfl_xor(s, 1, 64); s += __shfl_xor(s, 2, 64);
            s += __shfl_xor(s, 4, 64); s += __shfl_xor(s, 8, 64);
            s = fmaxf(s, 1e-20f);
            const float invS = __builtin_amdgcn_rcpf(s);
#pragma unroll
            for (int nt = 0; nt < 4; ++nt) {
                recC[nt][r] = tC[nt][r] * invS;
                qC[nt][r] = inpC[nt][r] * s * __builtin_amdgcn_rcpf(tC[nt][r]);
            }
        }
        floatx4 u[4];
        mfma_matvec(qC, T, lm, lq, WwH, WwL, u);
#pragma unroll
        for (int nt = 0; nt < 4; ++nt)
#pragma unroll
            for (int r = 0; r < 4; ++r)
                hC[nt][r] = fmaxf(hC[nt][r] * u[nt][r], 1e-6f);
#pragma unroll
        for (int r = 0; r < 4; ++r) {
            float s = (hC[0][r] + hC[1][r]) + (hC[2][r] + hC[3][r]);
            s += __shfl_xor(s, 1, 64); s += __shfl_xor(s, 2, 64);
            s += __shfl_xor(s, 4, 64); s += __shfl_xor(s, 8, 64);
            const float inv = __builtin_amdgcn_rcpf(fmaxf(s, 1e-20f));
#pragma unroll
            for (int nt = 0; nt < 4; ++nt) hC[nt][r] *= inv;
        }
    }
#pragma unroll
    for (int r = 0; r < 4; ++r) {   // normalize_h
        float s = (hC[0][r] + hC[1][r]) + (hC[2][r] + hC[3][r]);
        s += __shfl_xor(s, 1, 64); s += __shfl_xor(s, 2, 64);
        s += __shfl_xor(s, 4, 64); s += __shfl_xor(s, 8, 64);
        const float inv = __builtin_amdgcn_rcpf(fmaxf(s, 1e-20f));
#pragma unroll
        for (int nt = 0; nt < 4; ++nt) hC[nt][r] *= inv;
    }

    // stores: h, rec*inp row-major [o][f]
#pragma unroll
    for (int nt = 0; nt < 4; ++nt)
#pragma unroll
        for (int r = 0; r < 4; ++r) {
            const size_t o = (rowbase + lq * 4 + r) * 64 + nt * 16 + lm;
            hout[o] = hC[nt][r];
            hriout[o] = recC[nt][r] * inpC[nt][r];
        }

    // per-block partial of sum_o h[o,f]: wave-reduce + LDS combine + plain store
    float hs[4];
#pragma unroll
    for (int nt = 0; nt < 4; ++nt) {
        float s = (hC[nt][0] + hC[nt][1]) + (hC[nt][2] + hC[nt][3]);
        s += __shfl_xor(s, 16, 64);
        s += __shfl_xor(s, 32, 64);
        hs[nt] = s;
    }
    pbuf[wv * 64 + lq * 16 + lm] = hs[lq];
    __syncthreads();
    if (tid < 64) {
        float tot = (pbuf[tid] + pbuf[64 + tid]) + (pbuf[128 + tid] + pbuf[192 + tid]);
        mp0[(obase >> 6) * 64 + tid] = tot;
    }
}

// ---------------------------------------------------------------------------
// K4: one alpha iteration per launch, 384 blocks = (bh) x (64-o chunk).
// All outputs are exclusive plain stores.
// ---------------------------------------------------------------------------
__global__ __launch_bounds__(256) void k_alpha_step(const float* __restrict__ hin,
                                                    const float* __restrict__ hri,
                                                    const float* __restrict__ Wn,
                                                    const float* __restrict__ mp_in,
                                                    float* __restrict__ mp_out,
                                                    float* __restrict__ c,
                                                    int it) {
    __shared__ float mred[4][64];
    __shared__ float mv[64];
    __shared__ float vv[64];
    __shared__ float cl[64];
    const int tid = threadIdx.x;
    const int bh = blockIdx.x >> 4;
    const int chunk = blockIdx.x & 15;
    const size_t rowbase = (size_t)bh * 1024 + chunk * 64;

    {
        int f = tid & 63, p = tid >> 6;
        float s = 0.f;
#pragma unroll
        for (int pp = 0; pp < 4; ++pp)
            s += mp_in[((size_t)bh * 16 + p * 4 + pp) * 64 + f];
        mred[p][f] = s;
    }
    __syncthreads();
    if (tid < 64)
        mv[tid] = (mred[0][tid] + mred[1][tid]) + (mred[2][tid] + mred[3][tid]);
    __syncthreads();
    {
        int d = tid & 63, qq = tid >> 6;
        float r = 0.f;
#pragma unroll
        for (int ff = 0; ff < 16; ++ff)
            r = fmaf(mv[qq * 16 + ff], Wn[(size_t)(qq * 16 + ff) * 64 + d], r);
        mred[qq][d] = r;
    }
    __syncthreads();
    if (tid < 64)
        vv[tid] = 1.f / (((mred[0][tid] + mred[1][tid]) + (mred[2][tid] + mred[3][tid])) + 1e-20f);
    __syncthreads();
    {
        int o = tid >> 2, dq = tid & 3;
        const float* rp = hri + (rowbase + o) * 64 + dq * 16;
        float dot = 0.f;
#pragma unroll
        for (int t4 = 0; t4 < 16; t4 += 4) {
            float4 r4 = *(const float4*)(rp + t4);
            dot = fmaf(r4.x, vv[dq * 16 + t4 + 0], dot);
            dot = fmaf(r4.y, vv[dq * 16 + t4 + 1], dot);
            dot = fmaf(r4.z, vv[dq * 16 + t4 + 2], dot);
            dot = fmaf(r4.w, vv[dq * 16 + t4 + 3], dot);
        }
        dot += __shfl_xor(dot, 1, 64);
        dot += __shfl_xor(dot, 2, 64);
        float cn = dot;
        if (it >= 2) cn *= c[rowbase + o];
        if (dq == 0) { c[rowbase + o] = cn; cl[o] = cn; }
    }
    __syncthreads();
    {
        const int f4 = (tid & 15) * 4, ogr = tid >> 4;
        float4 a = make_float4(0.f, 0.f, 0.f, 0.f);
#pragma unroll
        for (int oi = 0; oi < 4; ++oi) {
            int o = ogr * 4 + oi;
            float4 h4 = *(const float4*)(hin + (rowbase + o) * 64 + f4);
            float cv = cl[o];
            a.x = fmaf(h4.x, cv, a.x); a.y = fmaf(h4.y, cv, a.y);
            a.z = fmaf(h4.z, cv, a.z); a.w = fmaf(h4.w, cv, a.w);
        }
        a.x += __shfl_xor(a.x, 16, 64); a.y += __shfl_xor(a.y, 16, 64);
        a.z += __shfl_xor(a.z, 16, 64); a.w += __shfl_xor(a.w, 16, 64);
        a.x += __shfl_xor(a.x, 32, 64); a.y += __shfl_xor(a.y, 32, 64);
        a.z += __shfl_xor(a.z, 32, 64); a.w += __shfl_xor(a.w, 32, 64);
        const int w = tid >> 6;
        if ((tid & 63) < 16) *(float4*)&mred[w][(tid & 15) * 4] = a;
    }
    __syncthreads();
    if (tid < 64) {
        float s = (mred[0][tid] + mred[1][tid]) + (mred[2][tid] + mred[3][tid]);
        mp_out[((size_t)bh * 16 + chunk) * 64 + tid] = s;
    }
}

// ---------------------------------------------------------------------------
// K5: out-projection + broadcast, 384 blocks = (b) x (12 out-seg) x (16 rowgrp).
// Folds the final 16-chunk M reduction into the Ml load.
// ---------------------------------------------------------------------------
__global__ __launch_bounds__(256) void k_projbcast(const float* __restrict__ mp3,
                                                   const float* __restrict__ ow,
                                                   const float* __restrict__ ob,
                                                   float* __restrict__ out) {
    __shared__ float Ml[768];
    __shared__ float ps[4][64];
    __shared__ float yseg[64];
    const int tid = threadIdx.x;
    const int b = blockIdx.x / 192;
    const int rem = blockIdx.x - b * 192;
    const int jt = rem >> 4, rg = rem & 15;
    for (int i = tid; i < 768; i += 256) {
        const int hh = i >> 6, f = i & 63;
        const float* src = mp3 + ((size_t)(b * 12 + hh) * 16) * 64 + f;
        float s = 0.f;
#pragma unroll
        for (int cc = 0; cc < 16; ++cc) s += src[cc * 64];
        Ml[i] = s;
    }
    __syncthreads();
    const int jj = tid & 63, part = tid >> 6;
    const int j = jt * 64 + jj;
    const float* row = ow + (size_t)j * 768 + part * 192;
    float acc = 0.f;
    for (int t = 0; t < 192; t += 4) {
        float4 w4 = *(const float4*)(row + t);
        acc = fmaf(w4.x, Ml[part * 192 + t + 0], acc);
        acc = fmaf(w4.y, Ml[part * 192 + t + 1], acc);
        acc = fmaf(w4.z, Ml[part * 192 + t + 2], acc);
        acc = fmaf(w4.w, Ml[part * 192 + t + 3], acc);
    }
    ps[part][jj] = acc;
    __syncthreads();
    if (tid < 64)
        yseg[tid] = ps[0][tid] + ps[1][tid] + ps[2][tid] + ps[3][tid] + ob[jt * 64 + tid];
    __syncthreads();
    const int r0 = tid >> 2, c4 = (tid & 3) * 16;
    float4 v4[4];
#pragma unroll
    for (int q = 0; q < 4; ++q) v4[q] = *(const float4*)&yseg[c4 + q * 4];
    float* dst = out + ((size_t)(b * 1024 + rg * 64 + r0)) * 768 + jt * 64 + c4;
#pragma unroll
    for (int q = 0; q < 4; ++q) *(float4*)(dst + q * 4) = v4[q];
}

extern "C" void kernel_launch(void* const* d_in, const int* in_sizes, int n_in,
                              void* d_out, int out_size, void* d_ws, size_t ws_size,
                              hipStream_t stream) {
    const float* xs = (const float*)d_in[0];  // [2,1024,768]
    const float* ew = (const float*)d_in[1];  // [768,768]
    const float* eb = (const float*)d_in[2];  // [768]
    const float* nw = (const float*)d_in[3];  // [64,64]
    const float* ow = (const float*)d_in[4];  // [768,768]
    const float* ob = (const float*)d_in[5];  // [768]
    float* out = (float*)d_out;               // [2,1024,768]

    float* ws    = (float*)d_ws;
    float* h     = ws + 1572864;           // 1572864 f
    float* hri   = ws + 3145728;           // 1572864 f
    float* Wn    = ws + 4718592;           // 4096 f
    float* r1inv = ws + 4722688;           // 256 f
    float* mp0   = ws + 4722944;           // 24576 f
    float* mp1   = ws + 4747520;           // 24576 f
    float* mp2   = ws + 4772096;           // 24576 f
    float* c     = ws + 4796672;           // 24576 f
    ushort* xsH  = (ushort*)(ws + 4821248);    // 1572864 us (786432 f)
    ushort* xsL  = (ushort*)(ws + 5607680);    // 1572864 us
    ushort* ewH  = (ushort*)(ws + 6394112);    // 589824 us (294912 f)
    ushort* ewL  = (ushort*)(ws + 6689024);    // 589824 us
    ushort* Wfrag= (ushort*)(ws + 6983936);    // 16384 us (8192 f)

    k_conv<<<1057, 256, 0, stream>>>(xs, ew, nw, xsH, xsL, ewH, ewL, Wn, r1inv, Wfrag);
    k_embed_nnmf<<<384, 256, 0, stream>>>(xsH, xsL, ewH, ewL, eb, Wfrag, r1inv, h, hri, mp0);
    k_alpha_step<<<384, 256, 0, stream>>>(h, hri, Wn, mp0, mp1, c, 1);
    k_alpha_step<<<384, 256, 0, stream>>>(h, hri, Wn, mp1, mp2, c, 2);
    k_alpha_step<<<384, 256, 0, stream>>>(h, hri, Wn, mp2, mp1, c, 3);
    k_projbcast<<<384, 256, 0, stream>>>(mp1, ow, ob, out);
}